// Round 2
// baseline (311.344 us; speedup 1.0000x reference)
//
#include <hip/hip_runtime.h>

typedef __bf16 bf16;
typedef __attribute__((ext_vector_type(8))) __bf16 bf16x8;
typedef __attribute__((ext_vector_type(4))) __bf16 bf16x4;
typedef __attribute__((ext_vector_type(4))) float f32x4;

#define S_LEN 2048
#define DM 1024
#define NB 4

// ---- async 16B global -> LDS (global_load_lds_dwordx4) ----
__device__ __forceinline__ void async_copy16(const void* g, void* l)
{
    __builtin_amdgcn_global_load_lds(
        (const __attribute__((address_space(1))) unsigned int*)g,
        (__attribute__((address_space(3))) unsigned int*)l,
        16, 0, 0);
}

#define VM_WAIT8 asm volatile("s_waitcnt vmcnt(8)" ::: "memory")
#define VM_WAIT0 asm volatile("s_waitcnt vmcnt(0)" ::: "memory")
#define VM_WAIT(n) asm volatile("s_waitcnt vmcnt(" #n ")" ::: "memory")
#define LGKM0    asm volatile("s_waitcnt lgkmcnt(0)" ::: "memory")
#define BAR      asm volatile("s_barrier" ::: "memory")
#define SCHED0   __builtin_amdgcn_sched_barrier(0)

// =====================================================================
// 256x256 NT GEMM, BK=64, 8 waves (2M x 4N), 8-phase counted-vmcnt
// schedule. LDS 128 KiB: buf0.A @0, buf0.B @32K, buf1.A @64K, buf1.B @96K.
// XOR chunk swizzle (phys16B = logical ^ (row&7)) via pre-swizzled global
// source; linear DMA dest; swizzled ds_read.
//
// ROUND-2 FIX (round-1 was racy + over-drained): stage slots reordered so
// every buffer's newest half is >= 2 slots (4 loads) older than its read,
// making vmcnt(4) at p4/p8 the ONLY in-loop waits, provably safe:
//   reads:  p1-p4 <- buf0 (tile kt)   p5-p8 <- buf1 (tile kt+1)
//   stages: p1:buf1.A0(kt+1) p2:buf1.A1(kt+1)   [A free after prev p7]
//           p3:buf0.B0(kt+2) p4:buf0.B1(kt+2)   [B free after p2]
//           p5:buf0.A0(kt+2) p6:buf0.A1(kt+2)   [A free after p3]
//           p7:buf1.B0(kt+3) p8:buf1.B1(kt+3)   [B free after p6]
//   p4-end vmcnt(4): outstanding = {p3,p4}; buf1 complete (p1,p2,prev p7/p8
//     retired) -> p5-p8 safe.
//   p8-end vmcnt(4): outstanding = {p7,p8}; buf0 complete (p3..p6 retired)
//     -> next p1-p4 safe.
// Tail prefetches clamped (re-stage kt) so counts stay valid.
// =====================================================================

__device__ __forceinline__ void read_half_A(const char* base, int wr, int mh,
                                            int l16, int quad, int swz,
                                            bf16x8 (&af)[4][2])
{
#pragma unroll
    for (int t = 0; t < 4; t++) {
        const char* rp = base + (wr * 128 + mh * 64 + t * 16 + l16) * 128;
        af[t][0] = *(const bf16x8*)(rp + ((quad ^ swz) << 4));
        af[t][1] = *(const bf16x8*)(rp + (((4 + quad) ^ swz) << 4));
    }
}

__device__ __forceinline__ void read_half_B(const char* base, int wc, int nh,
                                            int l16, int quad, int swz,
                                            bf16x8 (&bfr)[4][2])
{
#pragma unroll
    for (int u = 0; u < 2; u++) {
        const char* rp = base + (wc * 64 + nh * 32 + u * 16 + l16) * 128;
        bfr[nh * 2 + u][0] = *(const bf16x8*)(rp + ((quad ^ swz) << 4));
        bfr[nh * 2 + u][1] = *(const bf16x8*)(rp + (((4 + quad) ^ swz) << 4));
    }
}

// MH/NH literal constants (static acc indexing; rule #20)
#define MFMA_Q(MH, NH) do {                                                   \
    __builtin_amdgcn_s_setprio(1);                                            \
    _Pragma("unroll")                                                         \
    for (int kk = 0; kk < 2; kk++)                                            \
    _Pragma("unroll")                                                         \
    for (int mt = 0; mt < 4; mt++)                                            \
    _Pragma("unroll")                                                         \
    for (int nn = 0; nn < 2; nn++)                                            \
        acc[(MH)*4 + mt][(NH)*2 + nn] = __builtin_amdgcn_mfma_f32_16x16x32_bf16( \
            af[mt][kk], bfr[(NH)*2 + nn][kk], acc[(MH)*4 + mt][(NH)*2 + nn], 0, 0, 0); \
    __builtin_amdgcn_s_setprio(0);                                            \
} while (0)

#define STAGE(Xg, ld2, ktt, h, lbase) do {                                    \
    const char* _g = (Xg) + (size_t)(ktt) * 128 + (size_t)(h) * 128 * (ld2);  \
    async_copy16(_g,              (lbase) + (h) * 16384);                     \
    async_copy16(_g + 64 * (ld2), (lbase) + (h) * 16384 + 8192);              \
} while (0)

// A: 256 rows x K (row-major, lda); B: 256 rows x K (ldb). nt even, >=2.
__device__ __forceinline__ void gemm256(
    const bf16* __restrict__ A, int lda,
    const bf16* __restrict__ B, int ldb,
    int nt, char* smem, f32x4 (&acc)[8][4])
{
    const int tid = threadIdx.x;
    const int w = tid >> 6, lane = tid & 63;
    const int quad = lane >> 4, l16 = lane & 15;
    const int wr = w >> 2, wc = w & 3;
    const int swz = l16 & 7;

#pragma unroll
    for (int i = 0; i < 8; i++)
#pragma unroll
        for (int j = 0; j < 4; j++) acc[i][j] = f32x4{0.f, 0.f, 0.f, 0.f};

    const size_t lda2 = (size_t)lda * 2, ldb2 = (size_t)ldb * 2;
    const int srow = tid >> 3;                       // 0..63
    const int scol = ((tid & 7) ^ (srow & 7)) << 4;  // pre-swizzled source
    const char* aG = (const char*)A + (size_t)srow * lda2 + scol;
    const char* bG = (const char*)B + (size_t)srow * ldb2 + scol;
    char* const lsw = smem + w * 1024;               // wave-uniform DMA base

    bf16x8 af[4][2], bfr[4][2];

    // prologue: buf0{B0,B1,A0,A1}(k0), buf1{B0,B1}(k1) -> 12 loads/thread
    STAGE(bG, ldb2, 0, 0, lsw + 32768);
    STAGE(bG, ldb2, 0, 1, lsw + 32768);
    STAGE(aG, lda2, 0, 0, lsw);
    STAGE(aG, lda2, 0, 1, lsw);
    STAGE(bG, ldb2, 1, 0, lsw + 98304);
    STAGE(bG, ldb2, 1, 1, lsw + 98304);
    VM_WAIT(4); BAR;   // buf0 complete block-wide (buf1.B still in flight)

    for (int kt = 0; kt < nt; kt += 2) {
        const int k1 = kt + 1;
        const int k2 = (kt + 2 < nt) ? kt + 2 : kt;   // clamp: keep counts valid
        const int k3 = (kt + 3 < nt) ? kt + 3 : kt;

        // ---- p1: buf0 Q(0,0) | stage buf1.A0(k1) ----
        read_half_A(smem,          wr, 0, l16, quad, swz, af);
        read_half_B(smem + 32768,  wc, 0, l16, quad, swz, bfr);
        STAGE(aG, lda2, k1, 0, lsw + 65536);
        BAR; LGKM0; SCHED0;
        MFMA_Q(0, 0);
        BAR;
        // ---- p2: buf0 Q(0,1) | stage buf1.A1(k1) ----
        read_half_B(smem + 32768,  wc, 1, l16, quad, swz, bfr);
        STAGE(aG, lda2, k1, 1, lsw + 65536);
        BAR; LGKM0; SCHED0;
        MFMA_Q(0, 1);
        BAR;
        // ---- p3: buf0 Q(1,1) | stage buf0.B0(k2) ----
        read_half_A(smem,          wr, 1, l16, quad, swz, af);
        STAGE(bG, ldb2, k2, 0, lsw + 32768);
        BAR; LGKM0; SCHED0;
        MFMA_Q(1, 1);
        BAR;
        // ---- p4: buf0 Q(1,0) | stage buf0.B1(k2) | WAIT ----
        STAGE(bG, ldb2, k2, 1, lsw + 32768);
        BAR;
        MFMA_Q(1, 0);
        VM_WAIT(4); BAR;   // buf1(k1) complete
        // ---- p5: buf1 Q(0,0) | stage buf0.A0(k2) ----
        read_half_A(smem + 65536,  wr, 0, l16, quad, swz, af);
        read_half_B(smem + 98304,  wc, 0, l16, quad, swz, bfr);
        STAGE(aG, lda2, k2, 0, lsw);
        BAR; LGKM0; SCHED0;
        MFMA_Q(0, 0);
        BAR;
        // ---- p6: buf1 Q(0,1) | stage buf0.A1(k2) ----
        read_half_B(smem + 98304,  wc, 1, l16, quad, swz, bfr);
        STAGE(aG, lda2, k2, 1, lsw);
        BAR; LGKM0; SCHED0;
        MFMA_Q(0, 1);
        BAR;
        // ---- p7: buf1 Q(1,1) | stage buf1.B0(k3) ----
        read_half_A(smem + 65536,  wr, 1, l16, quad, swz, af);
        STAGE(bG, ldb2, k3, 0, lsw + 98304);
        BAR; LGKM0; SCHED0;
        MFMA_Q(1, 1);
        BAR;
        // ---- p8: buf1 Q(1,0) | stage buf1.B1(k3) | WAIT ----
        STAGE(bG, ldb2, k3, 1, lsw + 98304);
        BAR;
        MFMA_Q(1, 0);
        VM_WAIT(4); BAR;   // buf0(k2) complete
    }
    VM_WAIT0; BAR;   // drain clamped tail prefetches before smem reuse
}

// =====================================================================
// 128x128 core (proven) — used by pv
// =====================================================================

__device__ __forceinline__ void stage_issue(const char* aGk, size_t aRow32,
                                            const char* bGk, size_t bRow32,
                                            char* aL, char* bL)
{
#pragma unroll
    for (int i = 0; i < 4; i++) {
        async_copy16(aGk + i * aRow32, aL + i * 4096);
        async_copy16(bGk + i * bRow32, bL + i * 4096);
    }
}

__device__ __forceinline__ void read_frags(const char* bufA, const char* bufB,
                                           int wr, int wc, int l16, int quad,
                                           bf16x8 (&af)[2][4], bf16x8 (&bfr)[2][4])
{
    const int swz = l16 & 7;
#pragma unroll
    for (int kk = 0; kk < 2; kk++) {
        const int col = (((kk << 2) + quad) ^ swz) << 4;
#pragma unroll
        for (int t = 0; t < 4; t++) {
            af[kk][t]  = *(const bf16x8*)(bufA + (wr * 64 + t * 16 + l16) * 128 + col);
            bfr[kk][t] = *(const bf16x8*)(bufB + (wc * 64 + t * 16 + l16) * 128 + col);
        }
    }
}

__device__ __forceinline__ void mfma_all(const bf16x8 (&af)[2][4],
                                         const bf16x8 (&bfr)[2][4],
                                         f32x4 (&acc)[4][4])
{
#pragma unroll
    for (int kk = 0; kk < 2; kk++)
#pragma unroll
        for (int rt = 0; rt < 4; rt++)
#pragma unroll
            for (int ct = 0; ct < 4; ct++)
                acc[rt][ct] = __builtin_amdgcn_mfma_f32_16x16x32_bf16(
                    af[kk][rt], bfr[kk][ct], acc[rt][ct], 0, 0, 0);
}

__device__ __forceinline__ void gemm_tile(
    const bf16* __restrict__ A, int lda,
    const bf16* __restrict__ B, int ldb,
    int kSteps, char* smem, f32x4 (&acc)[4][4])
{
    const int tid = threadIdx.x;
    const int w = tid >> 6, lane = tid & 63;
    const int quad = lane >> 4, l16 = lane & 15;
    const int wr = w >> 1, wc = w & 1;

#pragma unroll
    for (int i = 0; i < 4; i++)
#pragma unroll
        for (int j = 0; j < 4; j++) acc[i][j] = f32x4{0.f, 0.f, 0.f, 0.f};

    const int srow = tid >> 3;
    const int sc8  = tid & 7;
    const int srcCol = (sc8 ^ (srow & 7)) * 16;
    const char* aG = (const char*)(A + (size_t)srow * lda) + srcCol;
    const char* bG = (const char*)(B + (size_t)srow * ldb) + srcCol;
    const size_t aRow32 = (size_t)lda * 64;
    const size_t bRow32 = (size_t)ldb * 64;
    char* aL0 = smem +     0 + w * 1024;
    char* bL0 = smem + 16384 + w * 1024;
    char* aL1 = smem + 32768 + w * 1024;
    char* bL1 = smem + 49152 + w * 1024;

    stage_issue(aG,       aRow32, bG,       bRow32, aL0, bL0);
    stage_issue(aG + 128, aRow32, bG + 128, bRow32, aL1, bL1);

    for (int ks = 0; ks < kSteps; ks += 2) {
        const bool more = (ks + 2 < kSteps);
        bf16x8 af[2][4], bfr[2][4];

        VM_WAIT8;
        BAR;
        read_frags(smem, smem + 16384, wr, wc, l16, quad, af, bfr);
        LGKM0;
        BAR;
        if (more)
            stage_issue(aG + (size_t)(ks + 2) * 128, aRow32,
                        bG + (size_t)(ks + 2) * 128, bRow32, aL0, bL0);
        mfma_all(af, bfr, acc);

        if (more) { VM_WAIT8; } else { VM_WAIT0; }
        BAR;
        read_frags(smem + 32768, smem + 49152, wr, wc, l16, quad, af, bfr);
        LGKM0;
        BAR;
        if (more)
            stage_issue(aG + (size_t)(ks + 3) * 128, aRow32,
                        bG + (size_t)(ks + 3) * 128, bRow32, aL1, bL1);
        mfma_all(af, bfr, acc);
    }
}

// ---- fp32 -> bf16 cast, 3 tensors, 8 elems/thread ----
__global__ __launch_bounds__(256) void cvt3_kernel(
    const float* __restrict__ s0, const float* __restrict__ s1, const float* __restrict__ s2,
    bf16* __restrict__ d0, bf16* __restrict__ d1, bf16* __restrict__ d2)
{
    const float* src = blockIdx.y == 0 ? s0 : blockIdx.y == 1 ? s1 : s2;
    bf16* dst        = blockIdx.y == 0 ? d0 : blockIdx.y == 1 ? d1 : d2;
    size_t i = ((size_t)blockIdx.x * 256 + threadIdx.x) * 8;
    f32x4 a = *(const f32x4*)(src + i);
    f32x4 b = *(const f32x4*)(src + i + 4);
    bf16x8 o;
    o[0] = (bf16)a[0]; o[1] = (bf16)a[1]; o[2] = (bf16)a[2]; o[3] = (bf16)a[3];
    o[4] = (bf16)b[0]; o[5] = (bf16)b[1]; o[6] = (bf16)b[2]; o[7] = (bf16)b[3];
    *(bf16x8*)(dst + i) = o;
}

// ---- projection: O = E @ W^T + b ; z==2 writes Vt[b][d][s] ----
// 256^2 tiles: 96 m-tiles x 4 n-tiles = 384 blocks x 512 thr.
__global__ __launch_bounds__(512, 2) void proj_kernel(
    const bf16* __restrict__ Eq, const bf16* __restrict__ Ek, const bf16* __restrict__ Ev,
    const bf16* __restrict__ Wq, const bf16* __restrict__ Wk, const bf16* __restrict__ Wv,
    const float* __restrict__ bq, const float* __restrict__ bk, const float* __restrict__ bv,
    bf16* __restrict__ Qo, bf16* __restrict__ Ko, bf16* __restrict__ Vt)
{
    __shared__ __align__(16) char smem[131072];
    const int bid = blockIdx.x;
    const int c = bid & 7;
    const int j = bid >> 3;          // 0..47
    const int z = j >> 4;            // 0..2
    const int jj = j & 15;
    const int T = c * 16 + jj;       // 0..127
    const int m0 = (T >> 2) * 256;
    const int n0 = (T & 3) * 256;

    const bf16* E     = z == 0 ? Eq : z == 1 ? Ek : Ev;
    const bf16* W     = z == 0 ? Wq : z == 1 ? Wk : Wv;
    const float* bias = z == 0 ? bq : z == 1 ? bk : bv;

    f32x4 acc[8][4];
    gemm256(E + (size_t)m0 * DM, DM, W + (size_t)n0 * DM, DM, DM / 64, smem, acc);

    const int tid = threadIdx.x;
    const int w = tid >> 6, lane = tid & 63;
    const int quad = lane >> 4, l16 = lane & 15;
    const int wr = w >> 2, wc = w & 3;
    const int nBase = n0 + wc * 64;

    float bcol[4];
#pragma unroll
    for (int ct = 0; ct < 4; ct++) bcol[ct] = bias[nBase + ct * 16 + l16];

    if (z < 2) {
        bf16* Tt = (bf16*)smem;   // 128 x 264 (rows 16B-aligned)
        bf16* O = z == 0 ? Qo : Ko;
#pragma unroll
        for (int h = 0; h < 2; h++) {
            if (wr == h) {
#pragma unroll
                for (int rt = 0; rt < 8; rt++)
#pragma unroll
                    for (int ct = 0; ct < 4; ct++)
#pragma unroll
                        for (int r = 0; r < 4; r++)
                            Tt[(rt * 16 + quad * 4 + r) * 264 + wc * 64 + ct * 16 + l16]
                                = (bf16)(acc[rt][ct][r] + bcol[ct]);
            }
            __syncthreads();
            const int row = tid >> 2, seg = tid & 3;
            const bf16* src = Tt + row * 264 + seg * 64;
            bf16* dst = O + (size_t)(m0 + h * 128 + row) * DM + n0 + seg * 64;
#pragma unroll
            for (int i = 0; i < 8; i++)
                *(bf16x8*)(dst + i * 8) = *(const bf16x8*)(src + i * 8);
            __syncthreads();
        }
    } else {
        // Vt[b][d][s]: lane holds 4 consecutive s for fixed d -> 8B store
#pragma unroll
        for (int rt = 0; rt < 8; rt++) {
            const int m = m0 + wr * 128 + rt * 16 + quad * 4;
            const int bb = m >> 11;
            const int s  = m & 2047;
#pragma unroll
            for (int ct = 0; ct < 4; ct++) {
                const int n = nBase + ct * 16 + l16;
                bf16x4 o;
                o[0] = (bf16)(acc[rt][ct][0] + bcol[ct]);
                o[1] = (bf16)(acc[rt][ct][1] + bcol[ct]);
                o[2] = (bf16)(acc[rt][ct][2] + bcol[ct]);
                o[3] = (bf16)(acc[rt][ct][3] + bcol[ct]);
                *(bf16x4*)(Vt + ((size_t)(bb * DM + n)) * S_LEN + s) = o;
            }
        }
    }
}

// ---- P = exp(Q K^T / 32) at 256^2 tiles; causal: 144 active blocks ----
__global__ __launch_bounds__(512, 2) void qk_kernel(
    const bf16* __restrict__ Q, const bf16* __restrict__ K,
    const int* __restrict__ maskp, bf16* __restrict__ P, float* __restrict__ lsum)
{
    const int bid = blockIdx.x;          // 0..255
    const bool causal = (maskp[0] != 0);
    int b, qt, kt;
    if (causal) {
        if (bid >= 144) return;          // 4 * 36 triangular tiles
        b = bid / 36;
        const int r = bid % 36;
        qt = 0;
        while ((qt + 1) * (qt + 2) / 2 <= r) qt++;   // qt 0..7
        kt = r - qt * (qt + 1) / 2;
    } else {
        b = bid >> 6;
        const int r = bid & 63;
        qt = r >> 3; kt = r & 7;
    }

    __shared__ __align__(16) char smem[131072];

    f32x4 acc[8][4];
    gemm256(Q + ((size_t)(b * S_LEN) + qt * 256) * DM, DM,
            K + ((size_t)(b * S_LEN) + kt * 256) * DM, DM, DM / 64, smem, acc);

    const int tid = threadIdx.x;
    const int w = tid >> 6, lane = tid & 63;
    const int quad = lane >> 4, l16 = lane & 15;
    const int wr = w >> 2, wc = w & 3;
    const float scale = 0.03125f;  // 1/sqrt(1024)

    bf16* Tt = (bf16*)smem;   // 128 x 264
    bf16* Pb = P + (size_t)b * S_LEN * S_LEN;
    float* lb = lsum + b * S_LEN;

#pragma unroll
    for (int h = 0; h < 2; h++) {
        if (wr == h) {
#pragma unroll
            for (int rt = 0; rt < 8; rt++)
#pragma unroll
                for (int r = 0; r < 4; r++) {
                    const int rloc = rt * 16 + quad * 4 + r;
                    const int qg = qt * 256 + h * 128 + rloc;
#pragma unroll
                    for (int ct = 0; ct < 4; ct++) {
                        const int kg = kt * 256 + wc * 64 + ct * 16 + l16;
                        const float p = (!causal || kg <= qg)
                                            ? __expf(acc[rt][ct][r] * scale) : 0.0f;
                        Tt[rloc * 264 + wc * 64 + ct * 16 + l16] = (bf16)p;
                    }
                }
        }
        __syncthreads();
        const int row = tid >> 2, seg = tid & 3;
        const bf16* src = Tt + row * 264 + seg * 64;
        bf16* dst = Pb + (size_t)(qt * 256 + h * 128 + row) * S_LEN + kt * 256 + seg * 64;
        float rs = 0.0f;
#pragma unroll
        for (int i = 0; i < 8; i++) {
            bf16x8 x = *(const bf16x8*)(src + i * 8);
            *(bf16x8*)(dst + i * 8) = x;
#pragma unroll
            for (int e = 0; e < 8; e++) rs += (float)x[e];  // sum rounded values PV uses
        }
        rs += __shfl_xor(rs, 1);
        rs += __shfl_xor(rs, 2);
        if ((tid & 3) == 0) atomicAdd(&lb[qt * 256 + h * 128 + row], rs);
        __syncthreads();
    }
}

// ---- O = (P @ Vt^T) / l ; ROUND-2: q-tile PAIRING for causal balance.
// Block (b, qp, dt) does qt = 15-qp then qt = qp sequentially:
// total K-steps = (16-qp)*2 + (qp+1)*2 = 34 for every block -> uniform
// makespan, grid 256 = 1 block/CU, shared Vt stripe (dt) stays L2-hot. ----
__global__ __launch_bounds__(256) void pv_kernel(
    const bf16* __restrict__ P, const bf16* __restrict__ Vt,
    const float* __restrict__ lsum, const int* __restrict__ maskp,
    float* __restrict__ Out)
{
    const int bid = blockIdx.x;          // 0..255
    const int dt = bid & 7;
    const int j = bid >> 3;              // 0..31
    const int b = j >> 3;                // 0..3
    const int qp = j & 7;                // 0..7
    const bool causal = (maskp[0] != 0);

    __shared__ __align__(16) char smem[65536];

    const int tid = threadIdx.x;
    const int w = tid >> 6, lane = tid & 63;
    const int quad = lane >> 4, l16 = lane & 15;
    const int wr = w >> 1, wc = w & 1;
    const float* lb = lsum + b * S_LEN;
    const bf16* Vb = Vt + ((size_t)(b * DM + dt * 128)) * S_LEN;

#pragma unroll
    for (int half = 0; half < 2; half++) {
        const int qt = half == 0 ? (15 - qp) : qp;   // long tile first
        const int kSteps = causal ? (qt + 1) * 2 : (S_LEN / 64);

        f32x4 acc[4][4];
        const bf16* Pb = P + ((size_t)b * S_LEN + qt * 128) * S_LEN;
        gemm_tile(Pb, S_LEN, Vb, S_LEN, kSteps, smem, acc);

        float inv[4][4];
#pragma unroll
        for (int rt = 0; rt < 4; rt++)
#pragma unroll
            for (int r = 0; r < 4; r++)
                inv[rt][r] = 1.0f / lb[qt * 128 + wr * 64 + rt * 16 + quad * 4 + r];

        __syncthreads();
        float* Ot = (float*)smem;   // 64 x 132
#pragma unroll
        for (int h = 0; h < 2; h++) {
            if (wr == h) {
#pragma unroll
                for (int rt = 0; rt < 4; rt++)
#pragma unroll
                    for (int r = 0; r < 4; r++) {
                        const int rloc = rt * 16 + quad * 4 + r;
#pragma unroll
                        for (int ct = 0; ct < 4; ct++)
                            Ot[rloc * 132 + wc * 64 + ct * 16 + l16] = acc[rt][ct][r] * inv[rt][r];
                    }
            }
            __syncthreads();
            const int row = tid >> 2, qq = tid & 3;
            const float* src = Ot + row * 132 + qq * 32;
            float* dst = Out + (size_t)(b * S_LEN + qt * 128 + h * 64 + row) * DM + dt * 128 + qq * 32;
#pragma unroll
            for (int i = 0; i < 8; i++)
                *(f32x4*)(dst + i * 4) = *(const f32x4*)(src + i * 4);
            __syncthreads();
        }
    }
}

extern "C" void kernel_launch(void* const* d_in, const int* in_sizes, int n_in,
                              void* d_out, int out_size, void* d_ws, size_t ws_size,
                              hipStream_t stream)
{
    const float* Eq = (const float*)d_in[0];
    const float* Ek = (const float*)d_in[1];
    const float* Ev = (const float*)d_in[2];
    const float* Wq = (const float*)d_in[3];
    const float* bq = (const float*)d_in[4];
    const float* Wk = (const float*)d_in[5];
    const float* bk = (const float*)d_in[6];
    const float* Wv = (const float*)d_in[7];
    const float* bv = (const float*)d_in[8];
    const int* maskp = (const int*)d_in[9];
    float* Out = (float*)d_out;

    // ws layout (~103 MB):
    //  [Qb 16M][Kb 16M][Vtb 16M][Wqb 2M][Wkb 2M][Wvb 2M][lsum 1M][P 32M | Eb overlay 48M]
    char* ws = (char*)d_ws;
    const size_t SZ_QKV = (size_t)NB * S_LEN * DM * 2;
    const size_t SZ_W   = (size_t)DM * DM * 2;
    bf16* Qb  = (bf16*)(ws);
    bf16* Kb  = (bf16*)(ws + SZ_QKV);
    bf16* Vtb = (bf16*)(ws + 2 * SZ_QKV);
    bf16* Wqb = (bf16*)(ws + 3 * SZ_QKV);
    bf16* Wkb = (bf16*)(ws + 3 * SZ_QKV + SZ_W);
    bf16* Wvb = (bf16*)(ws + 3 * SZ_QKV + 2 * SZ_W);
    float* lsum = (float*)(ws + 3 * SZ_QKV + 3 * SZ_W);
    bf16* Pbuf = (bf16*)(ws + 3 * SZ_QKV + 3 * SZ_W + (1 << 20));
    bf16* Eqb = Pbuf;   // E bf16 staging overlays P (dead once proj completes)
    bf16* Ekb = Eqb + (size_t)NB * S_LEN * DM;
    bf16* Evb = Ekb + (size_t)NB * S_LEN * DM;

    hipMemsetAsync(lsum, 0, (size_t)NB * S_LEN * 4, stream);
    cvt3_kernel<<<dim3(512, 3), 256, 0, stream>>>(Wq, Wk, Wv, Wqb, Wkb, Wvb);
    cvt3_kernel<<<dim3(4096, 3), 256, 0, stream>>>(Eq, Ek, Ev, Eqb, Ekb, Evb);

    proj_kernel<<<384, 512, 0, stream>>>(
        Eqb, Ekb, Evb, Wqb, Wkb, Wvb, bq, bk, bv, Qb, Kb, Vtb);

    qk_kernel<<<256, 512, 0, stream>>>(Qb, Kb, maskp, Pbuf, lsum);
    pv_kernel<<<256, 256, 0, stream>>>(Pbuf, Vtb, lsum, maskp, Out);
}

// Round 3
// 280.913 us; speedup vs baseline: 1.1083x; 1.1083x over previous
//
#include <hip/hip_runtime.h>

typedef __bf16 bf16;
typedef __attribute__((ext_vector_type(8))) __bf16 bf16x8;
typedef __attribute__((ext_vector_type(4))) __bf16 bf16x4;
typedef __attribute__((ext_vector_type(4))) float f32x4;

#define S_LEN 2048
#define DM 1024
#define NB 4

// ---- async 16B global -> LDS (global_load_lds_dwordx4) ----
__device__ __forceinline__ void async_copy16(const void* g, void* l)
{
    __builtin_amdgcn_global_load_lds(
        (const __attribute__((address_space(1))) unsigned int*)g,
        (__attribute__((address_space(3))) unsigned int*)l,
        16, 0, 0);
}

#define VM_WAIT8 asm volatile("s_waitcnt vmcnt(8)" ::: "memory")
#define VM_WAIT0 asm volatile("s_waitcnt vmcnt(0)" ::: "memory")
#define LGKM0    asm volatile("s_waitcnt lgkmcnt(0)" ::: "memory")
#define BAR      asm volatile("s_barrier" ::: "memory")

// =====================================================================
// 128x128 NT GEMM tile, BK=64, 4 waves (2x2), double-buffered LDS
// (2 x [A 16K | B 16K] = 64 KB -> 2 blocks/CU = 2 waves/SIMD).
// PROVEN round-0 core (795 TF on proj). The 2-blocks/CU co-residency is
// what overlaps LDS service with MFMA issue; the 256^2 1-block/CU port
// serialized them (measured 660 TF) and is abandoned.
// =====================================================================

__device__ __forceinline__ void stage_issue(const char* aGk, size_t aRow32,
                                            const char* bGk, size_t bRow32,
                                            char* aL, char* bL)
{
#pragma unroll
    for (int i = 0; i < 4; i++) {
        async_copy16(aGk + i * aRow32, aL + i * 4096);
        async_copy16(bGk + i * bRow32, bL + i * 4096);
    }
}

__device__ __forceinline__ void read_frags(const char* bufA, const char* bufB,
                                           int wr, int wc, int l16, int quad,
                                           bf16x8 (&af)[2][4], bf16x8 (&bfr)[2][4])
{
    const int swz = l16 & 7;
#pragma unroll
    for (int kk = 0; kk < 2; kk++) {
        const int col = (((kk << 2) + quad) ^ swz) << 4;
#pragma unroll
        for (int t = 0; t < 4; t++) {
            af[kk][t]  = *(const bf16x8*)(bufA + (wr * 64 + t * 16 + l16) * 128 + col);
            bfr[kk][t] = *(const bf16x8*)(bufB + (wc * 64 + t * 16 + l16) * 128 + col);
        }
    }
}

__device__ __forceinline__ void mfma_all(const bf16x8 (&af)[2][4],
                                         const bf16x8 (&bfr)[2][4],
                                         f32x4 (&acc)[4][4])
{
#pragma unroll
    for (int kk = 0; kk < 2; kk++)
#pragma unroll
        for (int rt = 0; rt < 4; rt++)
#pragma unroll
            for (int ct = 0; ct < 4; ct++)
                acc[rt][ct] = __builtin_amdgcn_mfma_f32_16x16x32_bf16(
                    af[kk][rt], bfr[kk][ct], acc[rt][ct], 0, 0, 0);
}

// A: 128 rows x K (row-major, lda elems); B: 128 rows x K (row-major, ldb).
// kSteps even. smem: 64 KB.
__device__ __forceinline__ void gemm_tile(
    const bf16* __restrict__ A, int lda,
    const bf16* __restrict__ B, int ldb,
    int kSteps, char* smem, f32x4 (&acc)[4][4])
{
    const int tid = threadIdx.x;
    const int w = tid >> 6, lane = tid & 63;
    const int quad = lane >> 4, l16 = lane & 15;
    const int wr = w >> 1, wc = w & 1;

#pragma unroll
    for (int i = 0; i < 4; i++)
#pragma unroll
        for (int j = 0; j < 4; j++) acc[i][j] = f32x4{0.f, 0.f, 0.f, 0.f};

    const int srow = tid >> 3;
    const int sc8  = tid & 7;
    const int srcCol = (sc8 ^ (srow & 7)) * 16;
    const char* aG = (const char*)(A + (size_t)srow * lda) + srcCol;
    const char* bG = (const char*)(B + (size_t)srow * ldb) + srcCol;
    const size_t aRow32 = (size_t)lda * 64;
    const size_t bRow32 = (size_t)ldb * 64;
    char* aL0 = smem +     0 + w * 1024;
    char* bL0 = smem + 16384 + w * 1024;
    char* aL1 = smem + 32768 + w * 1024;
    char* bL1 = smem + 49152 + w * 1024;

    stage_issue(aG,       aRow32, bG,       bRow32, aL0, bL0);   // tile 0 -> buf0
    stage_issue(aG + 128, aRow32, bG + 128, bRow32, aL1, bL1);   // tile 1 -> buf1

    for (int ks = 0; ks < kSteps; ks += 2) {
        const bool more = (ks + 2 < kSteps);
        bf16x8 af[2][4], bfr[2][4];

        // ---- phase A: consume buf0 (tile ks) ----
        VM_WAIT8;        // own tile-ks loads landed (tile ks+1 still in flight)
        BAR;             // all threads' tile-ks loads landed
        read_frags(smem, smem + 16384, wr, wc, l16, quad, af, bfr);
        LGKM0;           // frag data in registers
        BAR;             // all waves done reading buf0 -> safe to overwrite
        if (more)
            stage_issue(aG + (size_t)(ks + 2) * 128, aRow32,
                        bG + (size_t)(ks + 2) * 128, bRow32, aL0, bL0);
        mfma_all(af, bfr, acc);

        // ---- phase B: consume buf1 (tile ks+1) ----
        if (more) { VM_WAIT8; } else { VM_WAIT0; }
        BAR;
        read_frags(smem + 32768, smem + 49152, wr, wc, l16, quad, af, bfr);
        LGKM0;
        BAR;
        if (more)
            stage_issue(aG + (size_t)(ks + 3) * 128, aRow32,
                        bG + (size_t)(ks + 3) * 128, bRow32, aL1, bL1);
        mfma_all(af, bfr, acc);
    }
}

// ---- fp32 -> bf16 cast, 3 tensors, 8 elems/thread ----
__global__ __launch_bounds__(256) void cvt3_kernel(
    const float* __restrict__ s0, const float* __restrict__ s1, const float* __restrict__ s2,
    bf16* __restrict__ d0, bf16* __restrict__ d1, bf16* __restrict__ d2)
{
    const float* src = blockIdx.y == 0 ? s0 : blockIdx.y == 1 ? s1 : s2;
    bf16* dst        = blockIdx.y == 0 ? d0 : blockIdx.y == 1 ? d1 : d2;
    size_t i = ((size_t)blockIdx.x * 256 + threadIdx.x) * 8;
    f32x4 a = *(const f32x4*)(src + i);
    f32x4 b = *(const f32x4*)(src + i + 4);
    bf16x8 o;
    o[0] = (bf16)a[0]; o[1] = (bf16)a[1]; o[2] = (bf16)a[2]; o[3] = (bf16)a[3];
    o[4] = (bf16)b[0]; o[5] = (bf16)b[1]; o[6] = (bf16)b[2]; o[7] = (bf16)b[3];
    *(bf16x8*)(dst + i) = o;
}

// ---- projection Q,K only: O = E @ W^T + b. Grid 1024 (= exactly 2 full
// rounds at 2 blocks/CU). XCD c (bid&7) owns M-stripe, n-fastest. ----
__global__ __launch_bounds__(256) void projqk_kernel(
    const bf16* __restrict__ Eq, const bf16* __restrict__ Ek,
    const bf16* __restrict__ Wq, const bf16* __restrict__ Wk,
    const float* __restrict__ bq, const float* __restrict__ bk,
    bf16* __restrict__ Qo, bf16* __restrict__ Ko)
{
    __shared__ __align__(16) char smem[65536];
    const int bid = blockIdx.x;
    const int c = bid & 7;
    const int j = bid >> 3;          // 0..127
    const int z = j >> 6;            // 0..1
    const int r64 = j & 63;
    const int m0 = (c * 8 + (r64 >> 3)) * 128;
    const int n0 = (r64 & 7) * 128;

    const bf16* E     = z == 0 ? Eq : Ek;
    const bf16* W     = z == 0 ? Wq : Wk;
    const float* bias = z == 0 ? bq : bk;

    f32x4 acc[4][4];
    gemm_tile(E + (size_t)m0 * DM, DM, W + (size_t)n0 * DM, DM, DM / 64, smem, acc);

    const int tid = threadIdx.x;
    const int w = tid >> 6, lane = tid & 63;
    const int quad = lane >> 4, l16 = lane & 15;
    const int wr = w >> 1, wc = w & 1;
    const int nBase = n0 + wc * 64;

    float bcol[4];
#pragma unroll
    for (int ct = 0; ct < 4; ct++) bcol[ct] = bias[nBase + ct * 16 + l16];

    __syncthreads();   // smem reuse (no DMA outstanding after VM_WAIT0)
    bf16* Tt = (bf16*)smem;   // 128 x 136 (rows 16B-aligned)
#pragma unroll
    for (int rt = 0; rt < 4; rt++)
#pragma unroll
        for (int ct = 0; ct < 4; ct++)
#pragma unroll
            for (int r = 0; r < 4; r++)
                Tt[(wr * 64 + rt * 16 + quad * 4 + r) * 136 + wc * 64 + ct * 16 + l16]
                    = (bf16)(acc[rt][ct][r] + bcol[ct]);
    __syncthreads();
    bf16* O = z == 0 ? Qo : Ko;
    const int row = tid >> 1, half = tid & 1;
    const bf16* src = Tt + row * 136 + half * 64;
    bf16* dst = O + (size_t)(m0 + row) * DM + n0 + half * 64;
#pragma unroll
    for (int i = 0; i < 8; i++)
        *(bf16x8*)(dst + i * 8) = *(const bf16x8*)(src + i * 8);
}

// ---- MERGED: projV (blocks 0..511) + QK^T/exp (blocks 512..1535).
// qk's ~480 dead causal blocks retire instantly; projV backfills the slots.
// Memory-safe: qk writes P (overlays Eqb/Ekb staging only); projV reads Evb
// (disjoint overlay region) and writes Vtb. ----
__global__ __launch_bounds__(256) void projv_qk_kernel(
    const bf16* __restrict__ Ev, const bf16* __restrict__ Wv,
    const float* __restrict__ bv, bf16* __restrict__ Vt,
    const bf16* __restrict__ Q, const bf16* __restrict__ K,
    const int* __restrict__ maskp, bf16* __restrict__ P, float* __restrict__ lsum)
{
    __shared__ __align__(16) char smem[65536];
    const int bid = blockIdx.x;
    const int tid = threadIdx.x;
    const int w = tid >> 6, lane = tid & 63;
    const int quad = lane >> 4, l16 = lane & 15;
    const int wr = w >> 1, wc = w & 1;

    if (bid < 512) {
        // ================= projV: Vt[b][d][s] = (Ev @ Wv^T + bv)^T ======
        const int c = bid & 7;
        const int r64 = bid >> 3;        // 0..63
        const int m0 = (c * 8 + (r64 >> 3)) * 128;
        const int n0 = (r64 & 7) * 128;

        f32x4 acc[4][4];
        gemm_tile(Ev + (size_t)m0 * DM, DM, Wv + (size_t)n0 * DM, DM, DM / 64, smem, acc);

        const int nBase = n0 + wc * 64;
        float bcol[4];
#pragma unroll
        for (int ct = 0; ct < 4; ct++) bcol[ct] = bv[nBase + ct * 16 + l16];

        // Vt[b][d][s]: lane holds 4 consecutive s for fixed d -> 8B store
        const int mBase = m0 + wr * 64;
#pragma unroll
        for (int rt = 0; rt < 4; rt++) {
            const int m = mBase + rt * 16 + quad * 4;
            const int bb = m >> 11;
            const int s  = m & 2047;
#pragma unroll
            for (int ct = 0; ct < 4; ct++) {
                const int n = nBase + ct * 16 + l16;
                bf16x4 o;
                o[0] = (bf16)(acc[rt][ct][0] + bcol[ct]);
                o[1] = (bf16)(acc[rt][ct][1] + bcol[ct]);
                o[2] = (bf16)(acc[rt][ct][2] + bcol[ct]);
                o[3] = (bf16)(acc[rt][ct][3] + bcol[ct]);
                *(bf16x4*)(Vt + ((size_t)(bb * DM + n)) * S_LEN + s) = o;
            }
        }
    } else {
        // ================= qk: P = exp(Q K^T / 32), row sums =============
        const int qbid = bid - 512;          // 0..1023
        const int c = qbid & 7;
        const int j = qbid >> 3;             // 0..127
        const int b = j >> 5;
        const int jj = j & 31;
        const int kt = (jj < 16) ? c : (15 - c);
        const int qt = jj & 15;
        const bool causal = (maskp[0] != 0);
        if (causal && kt > qt) return;

        f32x4 acc[4][4];
        const bf16* Qb = Q + ((size_t)(b * S_LEN + qt * 128)) * DM;
        const bf16* Kb = K + ((size_t)(b * S_LEN + kt * 128)) * DM;
        gemm_tile(Qb, DM, Kb, DM, DM / 64, smem, acc);

        const float scale = 0.03125f;  // 1/sqrt(1024)

        __syncthreads();
        bf16* Pt = (bf16*)smem;   // 128 x 136
#pragma unroll
        for (int rt = 0; rt < 4; rt++)
#pragma unroll
            for (int r = 0; r < 4; r++) {
                const int rloc = wr * 64 + rt * 16 + quad * 4 + r;
                const int qg = qt * 128 + rloc;
#pragma unroll
                for (int ct = 0; ct < 4; ct++) {
                    const int kg = kt * 128 + wc * 64 + ct * 16 + l16;
                    float p = (!causal || kg <= qg) ? __expf(acc[rt][ct][r] * scale) : 0.0f;
                    Pt[rloc * 136 + wc * 64 + ct * 16 + l16] = (bf16)p;
                }
            }
        __syncthreads();

        bf16* Pb = P + (size_t)b * S_LEN * S_LEN;
        float* lb = lsum + b * S_LEN;
        const int row = tid >> 1, half = tid & 1;
        const bf16* src = Pt + row * 136 + half * 64;
        bf16* dst = Pb + (size_t)(qt * 128 + row) * S_LEN + kt * 128 + half * 64;
        float rs = 0.0f;
#pragma unroll
        for (int i = 0; i < 8; i++) {
            bf16x8 x = *(const bf16x8*)(src + i * 8);
            *(bf16x8*)(dst + i * 8) = x;
#pragma unroll
            for (int e = 0; e < 8; e++) rs += (float)x[e];   // sum rounded values PV uses
        }
        rs += __shfl_xor(rs, 1);
        if (half == 0) atomicAdd(&lb[qt * 128 + row], rs);
    }
}

// ---- O = (P @ Vt^T) / l. 512 blocks (2/CU). XCD-LOCAL remap: XCD c
// handles b=c>>1 with qt parity par=c&1; all 8 dt-blocks of a (b,qt)
// pair are consecutive on ONE XCD -> P-panel (<=512KB) is fetched once
// into that XCD's L2 (was: spread across 8 XCDs = 8x L3 re-reads).
// Vt[b] (4MB) pins to 2 XCDs. qt descending (long blocks first);
// parity split balances K-steps/XCD (64 vs 72). ----
__global__ __launch_bounds__(256) void pv_kernel(
    const bf16* __restrict__ P, const bf16* __restrict__ Vt,
    const float* __restrict__ lsum, const int* __restrict__ maskp,
    float* __restrict__ Out)
{
    const int bid = blockIdx.x;          // 0..511
    const int c = bid & 7;               // XCD
    const int b = c >> 1;
    const int par = c & 1;
    const int idx = bid >> 3;            // 0..63
    const int dt = idx & 7;
    const int qi = idx >> 3;             // 0..7
    const int qt = (7 - qi) * 2 + par;   // descending within XCD
    const bool causal = (maskp[0] != 0);
    const int kSteps = causal ? (qt + 1) * 2 : (S_LEN / 64);

    __shared__ __align__(16) char smem[65536];

    f32x4 acc[4][4];
    const bf16* Pb = P + ((size_t)b * S_LEN + qt * 128) * S_LEN;
    const bf16* Vb = Vt + ((size_t)(b * DM + dt * 128)) * S_LEN;
    gemm_tile(Pb, S_LEN, Vb, S_LEN, kSteps, smem, acc);

    const int tid = threadIdx.x;
    const int w = tid >> 6, lane = tid & 63;
    const int quad = lane >> 4, l16 = lane & 15;
    const int wr = w >> 1, wc = w & 1;

    const float* lb = lsum + b * S_LEN;
    float inv[4][4];
#pragma unroll
    for (int rt = 0; rt < 4; rt++)
#pragma unroll
        for (int r = 0; r < 4; r++)
            inv[rt][r] = 1.0f / lb[qt * 128 + wr * 64 + rt * 16 + quad * 4 + r];

    __syncthreads();
    float* Ot = (float*)smem;   // 64 x 132 (rows 16B-aligned)
#pragma unroll
    for (int h = 0; h < 2; h++) {
        if (wr == h) {
#pragma unroll
            for (int rt = 0; rt < 4; rt++)
#pragma unroll
                for (int r = 0; r < 4; r++) {
                    const int rloc = rt * 16 + quad * 4 + r;
#pragma unroll
                    for (int ct = 0; ct < 4; ct++)
                        Ot[rloc * 132 + wc * 64 + ct * 16 + l16] = acc[rt][ct][r] * inv[rt][r];
                }
        }
        __syncthreads();
        const int row = tid >> 2, qq = tid & 3;
        const float* src = Ot + row * 132 + qq * 32;
        float* dst = Out + (size_t)(b * S_LEN + qt * 128 + h * 64 + row) * DM + dt * 128 + qq * 32;
#pragma unroll
        for (int i = 0; i < 8; i++)
            *(f32x4*)(dst + i * 4) = *(const f32x4*)(src + i * 4);
        __syncthreads();
    }
}

extern "C" void kernel_launch(void* const* d_in, const int* in_sizes, int n_in,
                              void* d_out, int out_size, void* d_ws, size_t ws_size,
                              hipStream_t stream)
{
    const float* Eq = (const float*)d_in[0];
    const float* Ek = (const float*)d_in[1];
    const float* Ev = (const float*)d_in[2];
    const float* Wq = (const float*)d_in[3];
    const float* bq = (const float*)d_in[4];
    const float* Wk = (const float*)d_in[5];
    const float* bk = (const float*)d_in[6];
    const float* Wv = (const float*)d_in[7];
    const float* bv = (const float*)d_in[8];
    const int* maskp = (const int*)d_in[9];
    float* Out = (float*)d_out;

    // ws layout (~103 MB):
    //  [Qb 16M][Kb 16M][Vtb 16M][Wqb 2M][Wkb 2M][Wvb 2M][lsum 1M][P 32M | Eb overlay 48M]
    char* ws = (char*)d_ws;
    const size_t SZ_QKV = (size_t)NB * S_LEN * DM * 2;
    const size_t SZ_W   = (size_t)DM * DM * 2;
    bf16* Qb  = (bf16*)(ws);
    bf16* Kb  = (bf16*)(ws + SZ_QKV);
    bf16* Vtb = (bf16*)(ws + 2 * SZ_QKV);
    bf16* Wqb = (bf16*)(ws + 3 * SZ_QKV);
    bf16* Wkb = (bf16*)(ws + 3 * SZ_QKV + SZ_W);
    bf16* Wvb = (bf16*)(ws + 3 * SZ_QKV + 2 * SZ_W);
    float* lsum = (float*)(ws + 3 * SZ_QKV + 3 * SZ_W);
    bf16* Pbuf = (bf16*)(ws + 3 * SZ_QKV + 3 * SZ_W + (1 << 20));
    bf16* Eqb = Pbuf;   // E bf16 staging overlays P (dead once proj completes)
    bf16* Ekb = Eqb + (size_t)NB * S_LEN * DM;
    bf16* Evb = Ekb + (size_t)NB * S_LEN * DM;

    hipMemsetAsync(lsum, 0, (size_t)NB * S_LEN * 4, stream);
    cvt3_kernel<<<dim3(512, 3), 256, 0, stream>>>(Wq, Wk, Wv, Wqb, Wkb, Wvb);
    cvt3_kernel<<<dim3(4096, 3), 256, 0, stream>>>(Eq, Ek, Ev, Eqb, Ekb, Evb);

    projqk_kernel<<<1024, 256, 0, stream>>>(
        Eqb, Ekb, Wqb, Wkb, bq, bk, Qb, Kb);

    projv_qk_kernel<<<1536, 256, 0, stream>>>(
        Evb, Wvb, bv, Vtb, Qb, Kb, maskp, Pbuf, lsum);

    pv_kernel<<<512, 256, 0, stream>>>(Pbuf, Vtb, lsum, maskp, Out);
}